// Round 11
// baseline (306.676 us; speedup 1.0000x reference)
//
#include <hip/hip_runtime.h>
#include <hip/hip_fp16.h>

// ---------------------------------------------------------------------------
// GCN pipeline. Round 11 (= round-10 fixed): paired-edge gather — lanes 0-31
// take even edges, 32-63 odd edges, 8B (4 halves) per lane -> 2 rows (512B)
// in flight per load instruction; cross-half shfl_xor merge at end.
// Everything else = round 9 (validated).
// ---------------------------------------------------------------------------

typedef short bf16x8 __attribute__((ext_vector_type(8)));
typedef float f32x4  __attribute__((ext_vector_type(4)));
typedef float nfloat4 __attribute__((ext_vector_type(4)));

__device__ inline unsigned short f2bf_rne(float f) {
    unsigned u = __float_as_uint(f);
    unsigned r = (u + 0x7fffu + ((u >> 16) & 1u)) >> 16;
    return (unsigned short)r;
}
__device__ inline float bf2f(unsigned short h) {
    return __uint_as_float(((unsigned)h) << 16);
}
__device__ inline float2 u2f2(unsigned u) {          // 2 packed fp16 -> 2 fp32
    __half2 hv;
    *(unsigned*)&hv = u;
    return __half22float2(hv);
}

__global__ void hist_kernel(const int* __restrict__ dst, int* __restrict__ count, int E) {
    int e = blockIdx.x * blockDim.x + threadIdx.x;
    if (e < E) atomicAdd(&count[dst[e]], 1);
}

__global__ __launch_bounds__(256) void scan1_kernel(const int* __restrict__ count,
                                                    int* __restrict__ tmp,
                                                    int* __restrict__ bsum, int N) {
    __shared__ int s[256];
    int tid = threadIdx.x;
    int i = blockIdx.x * 256 + tid;
    int v = (i < N) ? count[i] : 0;
    s[tid] = v;
    __syncthreads();
#pragma unroll
    for (int off = 1; off < 256; off <<= 1) {
        int t = (tid >= off) ? s[tid - off] : 0;
        __syncthreads();
        s[tid] += t;
        __syncthreads();
    }
    if (i < N) tmp[i] = s[tid];
    if (tid == 255) bsum[blockIdx.x] = s[255];
}

// block 0: exclusive scan of block sums + zero pooled/cnt.
// blocks 1..128: weight split/transpose into MFMA fragment order.
__global__ __launch_bounds__(256) void scan2_wconv(const int* __restrict__ bsum,
                                                   int* __restrict__ boff, int nb,
                                                   float* __restrict__ pooled,
                                                   float* __restrict__ cnt,
                                                   const float* __restrict__ W1,
                                                   const float* __restrict__ W2,
                                                   unsigned short* __restrict__ W1h,
                                                   unsigned short* __restrict__ W1l,
                                                   unsigned short* __restrict__ W2h,
                                                   unsigned short* __restrict__ W2l) {
    int tid = threadIdx.x;
    if (blockIdx.x == 0) {
        __shared__ int s[256];
        int v = (tid < nb) ? bsum[tid] : 0;
        s[tid] = v;
        __syncthreads();
#pragma unroll
        for (int off = 1; off < 256; off <<= 1) {
            int t = (tid >= off) ? s[tid - off] : 0;
            __syncthreads();
            s[tid] += t;
            __syncthreads();
        }
        if (tid < nb) boff[tid] = s[tid] - v;   // exclusive
        for (int i = tid; i < 64 * 128; i += 256) pooled[i] = 0.f;
        if (tid < 64) cnt[tid] = 0.f;
        return;
    }
    int i = (blockIdx.x - 1) * 256 + tid;       // 0..32767
    const float* W = (i < 16384) ? W1 : W2;
    unsigned short* Wh = (i < 16384) ? W1h : W2h;
    unsigned short* Wl = (i < 16384) ? W1l : W2l;
    int ii = i & 16383;
    int k = ii >> 7, n = ii & 127;
    float v = W[ii];
    unsigned short h = f2bf_rne(v);
    float lo = v - bf2f(h);
    int ct = n >> 4, nn = n & 15, ks = k >> 5, q = (k >> 3) & 3, j = k & 7;
    int oidx = (((ct * 4 + ks) * 64) + (q * 16 + nn)) * 8 + j;
    Wh[oidx] = h;
    Wl[oidx] = f2bf_rne(lo);
}

// rowptr (exclusive), cursor copy, dinv
__global__ void finalize_kernel(const int* __restrict__ count, const int* __restrict__ tmp,
                                const int* __restrict__ boff, int* __restrict__ rowptr,
                                int* __restrict__ cursor, float* __restrict__ dinv, int N) {
    int i = blockIdx.x * blockDim.x + threadIdx.x;
    if (i > N) return;
    int ex = (i == 0) ? 0 : tmp[i - 1] + boff[(i - 1) >> 8];
    rowptr[i] = ex;
    if (i < N) {
        cursor[i] = ex;
        dinv[i] = 1.0f / sqrtf((float)count[i] + 1.0f);
    }
}

__global__ void reorder_kernel(const int* __restrict__ src, const int* __restrict__ dst,
                               const float* __restrict__ dinv,
                               int* __restrict__ cursor, int2* __restrict__ em, int E) {
    int e = blockIdx.x * blockDim.x + threadIdx.x;
    if (e < E) {
        int s = src[e], d = dst[e];
        int pos = atomicAdd(&cursor[d], 1);
        float norm = dinv[s] * dinv[d];
        em[pos] = make_int2(s, __float_as_int(norm));
    }
}

// ---- GEMM: OUT_fp16[M,128] = act(X_f32) @ W via bf16x3 MFMA -------------
template <bool RELU_IN>
__global__ __launch_bounds__(256) void gemm_mfma(const float* __restrict__ X,
                                                 const unsigned short* __restrict__ Wfh,
                                                 const unsigned short* __restrict__ Wfl,
                                                 __half* __restrict__ OUT, int M) {
    __shared__ unsigned short Xh[64][136];
    __shared__ unsigned short Xl[64][136];
    int tid = threadIdx.x;
    int w = tid >> 6, l = tid & 63;
    int m0 = blockIdx.x * 64;

#pragma unroll
    for (int it = 0; it < 8; it++) {
        int i = tid + it * 256;
        int row = i >> 5, c4 = i & 31;
        int grow = m0 + row;
        float4 v = make_float4(0.f, 0.f, 0.f, 0.f);
        if (grow < M) v = *(const float4*)(X + (size_t)grow * 128 + c4 * 4);
        if (RELU_IN) {
            v.x = fmaxf(v.x, 0.f); v.y = fmaxf(v.y, 0.f);
            v.z = fmaxf(v.z, 0.f); v.w = fmaxf(v.w, 0.f);
        }
        float a[4] = {v.x, v.y, v.z, v.w};
        ushort4 hi, lo;
        unsigned short* hp = (unsigned short*)&hi;
        unsigned short* lp = (unsigned short*)&lo;
#pragma unroll
        for (int e = 0; e < 4; e++) {
            unsigned short h = f2bf_rne(a[e]);
            hp[e] = h;
            lp[e] = f2bf_rne(a[e] - bf2f(h));
        }
        *(ushort4*)&Xh[row][c4 * 4] = hi;
        *(ushort4*)&Xl[row][c4 * 4] = lo;
    }
    __syncthreads();

    int q = l >> 4, nn = l & 15;
    f32x4 acc[8];
#pragma unroll
    for (int ct = 0; ct < 8; ct++) acc[ct] = (f32x4){0.f, 0.f, 0.f, 0.f};

#pragma unroll
    for (int ks = 0; ks < 4; ks++) {
        bf16x8 ahi = *(const bf16x8*)&Xh[w * 16 + nn][ks * 32 + q * 8];
        bf16x8 alo = *(const bf16x8*)&Xl[w * 16 + nn][ks * 32 + q * 8];
#pragma unroll
        for (int ct = 0; ct < 8; ct++) {
            size_t fo = ((size_t)(ct * 4 + ks) * 64 + l) * 8;
            bf16x8 bhi = *(const bf16x8*)(Wfh + fo);
            bf16x8 blo = *(const bf16x8*)(Wfl + fo);
            acc[ct] = __builtin_amdgcn_mfma_f32_16x16x32_bf16(ahi, bhi, acc[ct], 0, 0, 0);
            acc[ct] = __builtin_amdgcn_mfma_f32_16x16x32_bf16(alo, bhi, acc[ct], 0, 0, 0);
            acc[ct] = __builtin_amdgcn_mfma_f32_16x16x32_bf16(ahi, blo, acc[ct], 0, 0, 0);
        }
    }
    __syncthreads();   // done with Xh — reuse as fp16 epilogue buffer

#pragma unroll
    for (int r = 0; r < 4; r++) {
        int lrow = w * 16 + q * 4 + r;
#pragma unroll
        for (int ct = 0; ct < 8; ct++) {
            __half hv = __float2half(acc[ct][r]);
            Xh[lrow][ct * 16 + nn] = __half_as_ushort(hv);
        }
    }
    __syncthreads();
#pragma unroll
    for (int t = 0; t < 4; t++) {
        int c = tid + t * 256;
        int row = c >> 4, seg = c & 15;
        int grow = m0 + row;
        if (grow < M) {
            uint4 v = *(uint4*)&Xh[row][seg * 8];
            *(uint4*)((unsigned short*)OUT + (size_t)grow * 128 + seg * 8) = v;
        }
    }
}

// ---- gather: wave/node, paired edges, 8B/lane, fp32 accum ---------------
// lane = 32*p + c : p = edge parity, c = channel group (4 ch). Each load
// instruction fetches 2 rows x 256 B. Cross-half shfl_xor(32) merge at end.
__global__ __launch_bounds__(256) void gather_pair(const __half* __restrict__ h,
                                                   const float* __restrict__ dinv,
                                                   const float* __restrict__ bias,
                                                   const int* __restrict__ rowptr,
                                                   const long long* __restrict__ em,
                                                   float* __restrict__ B, int N) {
    int n = blockIdx.x * 4 + (threadIdx.x >> 6);
    int lane = threadIdx.x & 63;
    if (n >= N) return;
    int p = lane >> 5;          // edge parity
    int c = lane & 31;          // channel group (channels c*4..c*4+3)
    int beg = rowptr[n], end = rowptr[n + 1];

    float4 acc = make_float4(0.f, 0.f, 0.f, 0.f);
    int j = beg;
    // 8 edges per step = 4 paired loads per lane
    for (; j + 8 <= end; j += 8) {
        long long v0 = __builtin_nontemporal_load(em + j + p);
        long long v1 = __builtin_nontemporal_load(em + j + 2 + p);
        long long v2 = __builtin_nontemporal_load(em + j + 4 + p);
        long long v3 = __builtin_nontemporal_load(em + j + 6 + p);
        uint2 q0 = *(const uint2*)(h + (size_t)(int)v0 * 128 + c * 4);
        uint2 q1 = *(const uint2*)(h + (size_t)(int)v1 * 128 + c * 4);
        uint2 q2 = *(const uint2*)(h + (size_t)(int)v2 * 128 + c * 4);
        uint2 q3 = *(const uint2*)(h + (size_t)(int)v3 * 128 + c * 4);
        float n0 = __int_as_float((int)(v0 >> 32));
        float n1 = __int_as_float((int)(v1 >> 32));
        float n2 = __int_as_float((int)(v2 >> 32));
        float n3 = __int_as_float((int)(v3 >> 32));
        float2 a0 = u2f2(q0.x), b0 = u2f2(q0.y);
        float2 a1 = u2f2(q1.x), b1 = u2f2(q1.y);
        float2 a2 = u2f2(q2.x), b2 = u2f2(q2.y);
        float2 a3 = u2f2(q3.x), b3 = u2f2(q3.y);
        acc.x = fmaf(a0.x, n0, acc.x); acc.y = fmaf(a0.y, n0, acc.y);
        acc.z = fmaf(b0.x, n0, acc.z); acc.w = fmaf(b0.y, n0, acc.w);
        acc.x = fmaf(a1.x, n1, acc.x); acc.y = fmaf(a1.y, n1, acc.y);
        acc.z = fmaf(b1.x, n1, acc.z); acc.w = fmaf(b1.y, n1, acc.w);
        acc.x = fmaf(a2.x, n2, acc.x); acc.y = fmaf(a2.y, n2, acc.y);
        acc.z = fmaf(b2.x, n2, acc.z); acc.w = fmaf(b2.y, n2, acc.w);
        acc.x = fmaf(a3.x, n3, acc.x); acc.y = fmaf(a3.y, n3, acc.y);
        acc.z = fmaf(b3.x, n3, acc.z); acc.w = fmaf(b3.y, n3, acc.w);
    }
    // tail: pairs with masking (em padded; invalid lanes read own row, norm=0)
    for (; j < end; j += 2) {
        int jj = j + p;
        bool valid = jj < end;
        long long v = __builtin_nontemporal_load(em + jj);
        int s = valid ? (int)v : n;
        float nr = valid ? __int_as_float((int)(v >> 32)) : 0.f;
        uint2 qv = *(const uint2*)(h + (size_t)s * 128 + c * 4);
        float2 av = u2f2(qv.x), bv = u2f2(qv.y);
        acc.x = fmaf(av.x, nr, acc.x); acc.y = fmaf(av.y, nr, acc.y);
        acc.z = fmaf(bv.x, nr, acc.z); acc.w = fmaf(bv.y, nr, acc.w);
    }
    // merge the two edge-parity halves
    acc.x += __shfl_xor(acc.x, 32, 64);
    acc.y += __shfl_xor(acc.y, 32, 64);
    acc.z += __shfl_xor(acc.z, 32, 64);
    acc.w += __shfl_xor(acc.w, 32, 64);

    if (p == 0) {
        float din = dinv[n];
        float sw = din * din;
        uint2 qv = *(const uint2*)(h + (size_t)n * 128 + c * 4);
        float2 av = u2f2(qv.x), bv = u2f2(qv.y);
        float4 bi = *(const float4*)(bias + c * 4);
        nfloat4 o;
        o.x = fmaf(av.x, sw, acc.x) + bi.x;
        o.y = fmaf(av.y, sw, acc.y) + bi.y;
        o.z = fmaf(bv.x, sw, acc.z) + bi.z;
        o.w = fmaf(bv.y, sw, acc.w) + bi.w;
        __builtin_nontemporal_store(o, (nfloat4*)(B + (size_t)n * 128 + c * 4));
    }
}

// ---- pool: batch sorted -> run-length, atomics only at transitions ------
__global__ __launch_bounds__(256) void pool_kernel(const float* __restrict__ B,
                                                   const int* __restrict__ batch,
                                                   float* pooled, float* cnt, int N) {
    int c = threadIdx.x & 127;
    int half = threadIdx.x >> 7;
    int n0 = blockIdx.x * 128;
    float acc = 0.f, cacc = 0.f;
    int curg = -1;
    for (int i = half; i < 128; i += 2) {
        int n = n0 + i;
        if (n >= N) break;
        int g = batch[n];
        float v = fmaxf(B[(size_t)n * 128 + c], 0.f);
        if (g != curg) {
            if (curg >= 0) {
                atomicAdd(&pooled[curg * 128 + c], acc);
                if (c == 0) atomicAdd(&cnt[curg], cacc);
            }
            curg = g; acc = 0.f; cacc = 0.f;
        }
        acc += v; cacc += 1.f;
    }
    if (curg >= 0) {
        atomicAdd(&pooled[curg * 128 + c], acc);
        if (c == 0) atomicAdd(&cnt[curg], cacc);
    }
}

// ---- head: one wave per graph ------------------------------------------
__global__ __launch_bounds__(64) void head_kernel(const float* __restrict__ pooled,
                                                  const float* __restrict__ cnt,
                                                  const float* __restrict__ Wfc1,
                                                  const float* __restrict__ bfc1,
                                                  const float* __restrict__ Wfc2,
                                                  const float* __restrict__ bfc2,
                                                  float* __restrict__ out) {
    __shared__ float mean[128];
    int g = blockIdx.x;
    int t = threadIdx.x;
    float inv = 1.0f / fmaxf(cnt[g], 1.0f);
    mean[t] = pooled[g * 128 + t] * inv;
    mean[t + 64] = pooled[g * 128 + t + 64] * inv;
    __syncthreads();
    float s = bfc1[t];
#pragma unroll 4
    for (int k = 0; k < 128; k++) s = fmaf(mean[k], Wfc1[k * 64 + t], s);
    float p = fmaxf(s, 0.f) * Wfc2[t];
#pragma unroll
    for (int o = 32; o > 0; o >>= 1) p += __shfl_down(p, o, 64);
    if (t == 0) out[g] = p + bfc2[0];
}

extern "C" void kernel_launch(void* const* d_in, const int* in_sizes, int n_in,
                              void* d_out, int out_size, void* d_ws, size_t ws_size,
                              hipStream_t stream) {
    const float* x    = (const float*)d_in[0];
    const int*   edge = (const int*)d_in[1];
    const int*   batch= (const int*)d_in[2];
    const float* W1   = (const float*)d_in[3];
    const float* b1   = (const float*)d_in[4];
    const float* W2   = (const float*)d_in[5];
    const float* b2   = (const float*)d_in[6];
    const float* Wfc1 = (const float*)d_in[7];
    const float* bfc1 = (const float*)d_in[8];
    const float* Wfc2 = (const float*)d_in[9];
    const float* bfc2 = (const float*)d_in[10];
    float* out = (float*)d_out;

    int N = in_sizes[0] / 128;
    int E = in_sizes[1] / 2;
    const int* src = edge;
    const int* dst = edge + E;

    char* ws = (char*)d_ws;
    size_t off = 0;
    auto alloc = [&](size_t bytes) { void* p = ws + off; off += (bytes + 255) & ~(size_t)255; return p; };
    __half* Ah    = (__half*)alloc((size_t)N * 128 * sizeof(__half));   // gather operand
    float* B      = (float*)alloc((size_t)N * 128 * sizeof(float));     // gather out
    float* dinv   = (float*)alloc((size_t)N * sizeof(float));
    int*   count  = (int*)alloc((size_t)N * sizeof(int));
    int*   tmp    = (int*)alloc((size_t)N * sizeof(int));
    int*   rowptr = (int*)alloc((size_t)(N + 1) * sizeof(int));
    int*   cursor = (int*)alloc((size_t)N * sizeof(int));
    int2*  em     = (int2*)alloc((size_t)(E + 8) * sizeof(int2));       // +8 tail pad
    int*   bsum   = (int*)alloc(256 * sizeof(int));
    int*   boff   = (int*)alloc(256 * sizeof(int));
    float* pooled = (float*)alloc(64 * 128 * sizeof(float));
    float* cnt    = (float*)alloc(64 * sizeof(float));
    unsigned short* W1h = (unsigned short*)alloc(16384 * sizeof(short));
    unsigned short* W1l = (unsigned short*)alloc(16384 * sizeof(short));
    unsigned short* W2h = (unsigned short*)alloc(16384 * sizeof(short));
    unsigned short* W2l = (unsigned short*)alloc(16384 * sizeof(short));

    int nb = (N + 255) / 256;

    (void)hipMemsetAsync(count, 0, (size_t)N * sizeof(int), stream);

    // CSR build + weight prep (pooled/cnt zeroed in scan2_wconv blk 0)
    hist_kernel<<<(E + 255) / 256, 256, 0, stream>>>(dst, count, E);
    scan1_kernel<<<nb, 256, 0, stream>>>(count, tmp, bsum, N);
    scan2_wconv<<<129, 256, 0, stream>>>(bsum, boff, nb, pooled, cnt,
                                         W1, W2, W1h, W1l, W2h, W2l);
    finalize_kernel<<<(N + 256) / 256, 256, 0, stream>>>(count, tmp, boff, rowptr, cursor, dinv, N);
    reorder_kernel<<<(E + 255) / 256, 256, 0, stream>>>(src, dst, dinv, cursor, em, E);

    int gblocks = (N + 63) / 64;
    int ablocks = (N + 3) / 4;

    // Layer 1
    gemm_mfma<false><<<gblocks, 256, 0, stream>>>(x, W1h, W1l, Ah, N);
    gather_pair<<<ablocks, 256, 0, stream>>>(Ah, dinv, b1, rowptr, (const long long*)em, B, N);

    // Layer 2 (relu fused into GEMM staging)
    gemm_mfma<true><<<gblocks, 256, 0, stream>>>(B, W2h, W2l, Ah, N);
    gather_pair<<<ablocks, 256, 0, stream>>>(Ah, dinv, b2, rowptr, (const long long*)em, B, N);

    // Pool (relu fused) + head
    pool_kernel<<<(N + 127) / 128, 256, 0, stream>>>(B, batch, pooled, cnt, N);
    head_kernel<<<64, 64, 0, stream>>>(pooled, cnt, Wfc1, bfc1, Wfc2, bfc2, out);
}

// Round 12
// 291.383 us; speedup vs baseline: 1.0525x; 1.0525x over previous
//
#include <hip/hip_runtime.h>
#include <hip/hip_fp16.h>

// ---------------------------------------------------------------------------
// GCN pipeline. Round 12: revert to round-9 (validated best, 279 µs) + one
// change: nontemporal em loads in gather (metadata stream no longer evicts
// the fp16 h table from L2).
//  - GEMM: LDS-staged bf16x3 MFMA, frag-ordered W, fp16 output via LDS repack
//  - gather: wave/node, half2 row reads (256B/txn), 8x unroll, fp32 accum
//  - pool: run-length (atomics only at graph transitions)
// ---------------------------------------------------------------------------

typedef short bf16x8 __attribute__((ext_vector_type(8)));
typedef float f32x4  __attribute__((ext_vector_type(4)));

__device__ inline unsigned short f2bf_rne(float f) {
    unsigned u = __float_as_uint(f);
    unsigned r = (u + 0x7fffu + ((u >> 16) & 1u)) >> 16;
    return (unsigned short)r;
}
__device__ inline float bf2f(unsigned short h) {
    return __uint_as_float(((unsigned)h) << 16);
}

__global__ void hist_kernel(const int* __restrict__ dst, int* __restrict__ count, int E) {
    int e = blockIdx.x * blockDim.x + threadIdx.x;
    if (e < E) atomicAdd(&count[dst[e]], 1);
}

__global__ __launch_bounds__(256) void scan1_kernel(const int* __restrict__ count,
                                                    int* __restrict__ tmp,
                                                    int* __restrict__ bsum, int N) {
    __shared__ int s[256];
    int tid = threadIdx.x;
    int i = blockIdx.x * 256 + tid;
    int v = (i < N) ? count[i] : 0;
    s[tid] = v;
    __syncthreads();
#pragma unroll
    for (int off = 1; off < 256; off <<= 1) {
        int t = (tid >= off) ? s[tid - off] : 0;
        __syncthreads();
        s[tid] += t;
        __syncthreads();
    }
    if (i < N) tmp[i] = s[tid];
    if (tid == 255) bsum[blockIdx.x] = s[255];
}

// block 0: exclusive scan of block sums + zero pooled/cnt.
// blocks 1..128: weight split/transpose into MFMA fragment order.
// frag addr = ((ct*4+ks)*64 + (q*16+nn))*8 + j ; n=ct*16+nn, k=ks*32+q*8+j
__global__ __launch_bounds__(256) void scan2_wconv(const int* __restrict__ bsum,
                                                   int* __restrict__ boff, int nb,
                                                   float* __restrict__ pooled,
                                                   float* __restrict__ cnt,
                                                   const float* __restrict__ W1,
                                                   const float* __restrict__ W2,
                                                   unsigned short* __restrict__ W1h,
                                                   unsigned short* __restrict__ W1l,
                                                   unsigned short* __restrict__ W2h,
                                                   unsigned short* __restrict__ W2l) {
    int tid = threadIdx.x;
    if (blockIdx.x == 0) {
        __shared__ int s[256];
        int v = (tid < nb) ? bsum[tid] : 0;
        s[tid] = v;
        __syncthreads();
#pragma unroll
        for (int off = 1; off < 256; off <<= 1) {
            int t = (tid >= off) ? s[tid - off] : 0;
            __syncthreads();
            s[tid] += t;
            __syncthreads();
        }
        if (tid < nb) boff[tid] = s[tid] - v;   // exclusive
        for (int i = tid; i < 64 * 128; i += 256) pooled[i] = 0.f;
        if (tid < 64) cnt[tid] = 0.f;
        return;
    }
    int i = (blockIdx.x - 1) * 256 + tid;       // 0..32767
    const float* W = (i < 16384) ? W1 : W2;
    unsigned short* Wh = (i < 16384) ? W1h : W2h;
    unsigned short* Wl = (i < 16384) ? W1l : W2l;
    int ii = i & 16383;
    int k = ii >> 7, n = ii & 127;
    float v = W[ii];
    unsigned short h = f2bf_rne(v);
    float lo = v - bf2f(h);
    int ct = n >> 4, nn = n & 15, ks = k >> 5, q = (k >> 3) & 3, j = k & 7;
    int oidx = (((ct * 4 + ks) * 64) + (q * 16 + nn)) * 8 + j;
    Wh[oidx] = h;
    Wl[oidx] = f2bf_rne(lo);
}

// rowptr (exclusive), cursor copy, dinv
__global__ void finalize_kernel(const int* __restrict__ count, const int* __restrict__ tmp,
                                const int* __restrict__ boff, int* __restrict__ rowptr,
                                int* __restrict__ cursor, float* __restrict__ dinv, int N) {
    int i = blockIdx.x * blockDim.x + threadIdx.x;
    if (i > N) return;
    int ex = (i == 0) ? 0 : tmp[i - 1] + boff[(i - 1) >> 8];
    rowptr[i] = ex;
    if (i < N) {
        cursor[i] = ex;
        dinv[i] = 1.0f / sqrtf((float)count[i] + 1.0f);
    }
}

__global__ void reorder_kernel(const int* __restrict__ src, const int* __restrict__ dst,
                               const float* __restrict__ dinv,
                               int* __restrict__ cursor, int2* __restrict__ em, int E) {
    int e = blockIdx.x * blockDim.x + threadIdx.x;
    if (e < E) {
        int s = src[e], d = dst[e];
        int pos = atomicAdd(&cursor[d], 1);
        float norm = dinv[s] * dinv[d];
        em[pos] = make_int2(s, __float_as_int(norm));
    }
}

// ---- GEMM: OUT_fp16[M,128] = act(X_f32) @ W via bf16x3 MFMA -------------
template <bool RELU_IN>
__global__ __launch_bounds__(256) void gemm_mfma(const float* __restrict__ X,
                                                 const unsigned short* __restrict__ Wfh,
                                                 const unsigned short* __restrict__ Wfl,
                                                 __half* __restrict__ OUT, int M) {
    __shared__ unsigned short Xh[64][136];
    __shared__ unsigned short Xl[64][136];
    int tid = threadIdx.x;
    int w = tid >> 6, l = tid & 63;
    int m0 = blockIdx.x * 64;

#pragma unroll
    for (int it = 0; it < 8; it++) {
        int i = tid + it * 256;
        int row = i >> 5, c4 = i & 31;
        int grow = m0 + row;
        float4 v = make_float4(0.f, 0.f, 0.f, 0.f);
        if (grow < M) v = *(const float4*)(X + (size_t)grow * 128 + c4 * 4);
        if (RELU_IN) {
            v.x = fmaxf(v.x, 0.f); v.y = fmaxf(v.y, 0.f);
            v.z = fmaxf(v.z, 0.f); v.w = fmaxf(v.w, 0.f);
        }
        float a[4] = {v.x, v.y, v.z, v.w};
        ushort4 hi, lo;
        unsigned short* hp = (unsigned short*)&hi;
        unsigned short* lp = (unsigned short*)&lo;
#pragma unroll
        for (int e = 0; e < 4; e++) {
            unsigned short h = f2bf_rne(a[e]);
            hp[e] = h;
            lp[e] = f2bf_rne(a[e] - bf2f(h));
        }
        *(ushort4*)&Xh[row][c4 * 4] = hi;
        *(ushort4*)&Xl[row][c4 * 4] = lo;
    }
    __syncthreads();

    int q = l >> 4, nn = l & 15;
    f32x4 acc[8];
#pragma unroll
    for (int ct = 0; ct < 8; ct++) acc[ct] = (f32x4){0.f, 0.f, 0.f, 0.f};

#pragma unroll
    for (int ks = 0; ks < 4; ks++) {
        bf16x8 ahi = *(const bf16x8*)&Xh[w * 16 + nn][ks * 32 + q * 8];
        bf16x8 alo = *(const bf16x8*)&Xl[w * 16 + nn][ks * 32 + q * 8];
#pragma unroll
        for (int ct = 0; ct < 8; ct++) {
            size_t fo = ((size_t)(ct * 4 + ks) * 64 + l) * 8;
            bf16x8 bhi = *(const bf16x8*)(Wfh + fo);
            bf16x8 blo = *(const bf16x8*)(Wfl + fo);
            acc[ct] = __builtin_amdgcn_mfma_f32_16x16x32_bf16(ahi, bhi, acc[ct], 0, 0, 0);
            acc[ct] = __builtin_amdgcn_mfma_f32_16x16x32_bf16(alo, bhi, acc[ct], 0, 0, 0);
            acc[ct] = __builtin_amdgcn_mfma_f32_16x16x32_bf16(ahi, blo, acc[ct], 0, 0, 0);
        }
    }
    __syncthreads();   // done with Xh — reuse as fp16 epilogue buffer

#pragma unroll
    for (int r = 0; r < 4; r++) {
        int lrow = w * 16 + q * 4 + r;
#pragma unroll
        for (int ct = 0; ct < 8; ct++) {
            __half hv = __float2half(acc[ct][r]);
            Xh[lrow][ct * 16 + nn] = __half_as_ushort(hv);
        }
    }
    __syncthreads();
#pragma unroll
    for (int t = 0; t < 4; t++) {
        int c = tid + t * 256;
        int row = c >> 4, seg = c & 15;
        int grow = m0 + row;
        if (grow < M) {
            uint4 v = *(uint4*)&Xh[row][seg * 8];
            *(uint4*)((unsigned short*)OUT + (size_t)grow * 128 + seg * 8) = v;
        }
    }
}

// ---- gather: wave/node, fp16 operand, fp32 accum/out, 8x unroll ---------
// em loads nontemporal: one-shot metadata must not evict the h table from L2.
__global__ __launch_bounds__(256) void gather_half(const __half* __restrict__ h,
                                                   const float* __restrict__ dinv,
                                                   const float* __restrict__ bias,
                                                   const int* __restrict__ rowptr,
                                                   const long long* __restrict__ em,
                                                   float* __restrict__ B, int N) {
    int n = blockIdx.x * 4 + (threadIdx.x >> 6);
    int lane = threadIdx.x & 63;
    if (n >= N) return;
    int beg = rowptr[n], end = rowptr[n + 1];
    float din = dinv[n];
    const __half2* hp = (const __half2*)h;        // [N*64]
    float2 hv = __half22float2(hp[(size_t)n * 64 + lane]);
    float sw = din * din;
    float ax = hv.x * sw, ay = hv.y * sw;
    int j = beg;
    for (; j + 8 <= end; j += 8) {
        long long v0 = __builtin_nontemporal_load(em + j);
        long long v1 = __builtin_nontemporal_load(em + j + 1);
        long long v2 = __builtin_nontemporal_load(em + j + 2);
        long long v3 = __builtin_nontemporal_load(em + j + 3);
        long long v4 = __builtin_nontemporal_load(em + j + 4);
        long long v5 = __builtin_nontemporal_load(em + j + 5);
        long long v6 = __builtin_nontemporal_load(em + j + 6);
        long long v7 = __builtin_nontemporal_load(em + j + 7);
        float2 r0 = __half22float2(hp[(size_t)(int)v0 * 64 + lane]);
        float2 r1 = __half22float2(hp[(size_t)(int)v1 * 64 + lane]);
        float2 r2 = __half22float2(hp[(size_t)(int)v2 * 64 + lane]);
        float2 r3 = __half22float2(hp[(size_t)(int)v3 * 64 + lane]);
        float2 r4 = __half22float2(hp[(size_t)(int)v4 * 64 + lane]);
        float2 r5 = __half22float2(hp[(size_t)(int)v5 * 64 + lane]);
        float2 r6 = __half22float2(hp[(size_t)(int)v6 * 64 + lane]);
        float2 r7 = __half22float2(hp[(size_t)(int)v7 * 64 + lane]);
        float n0 = __int_as_float((int)(v0 >> 32));
        float n1 = __int_as_float((int)(v1 >> 32));
        float n2 = __int_as_float((int)(v2 >> 32));
        float n3 = __int_as_float((int)(v3 >> 32));
        float n4 = __int_as_float((int)(v4 >> 32));
        float n5 = __int_as_float((int)(v5 >> 32));
        float n6 = __int_as_float((int)(v6 >> 32));
        float n7 = __int_as_float((int)(v7 >> 32));
        ax = fmaf(r0.x, n0, ax); ay = fmaf(r0.y, n0, ay);
        ax = fmaf(r1.x, n1, ax); ay = fmaf(r1.y, n1, ay);
        ax = fmaf(r2.x, n2, ax); ay = fmaf(r2.y, n2, ay);
        ax = fmaf(r3.x, n3, ax); ay = fmaf(r3.y, n3, ay);
        ax = fmaf(r4.x, n4, ax); ay = fmaf(r4.y, n4, ay);
        ax = fmaf(r5.x, n5, ax); ay = fmaf(r5.y, n5, ay);
        ax = fmaf(r6.x, n6, ax); ay = fmaf(r6.y, n6, ay);
        ax = fmaf(r7.x, n7, ax); ay = fmaf(r7.y, n7, ay);
    }
    for (; j + 4 <= end; j += 4) {
        long long v0 = __builtin_nontemporal_load(em + j);
        long long v1 = __builtin_nontemporal_load(em + j + 1);
        long long v2 = __builtin_nontemporal_load(em + j + 2);
        long long v3 = __builtin_nontemporal_load(em + j + 3);
        float2 r0 = __half22float2(hp[(size_t)(int)v0 * 64 + lane]);
        float2 r1 = __half22float2(hp[(size_t)(int)v1 * 64 + lane]);
        float2 r2 = __half22float2(hp[(size_t)(int)v2 * 64 + lane]);
        float2 r3 = __half22float2(hp[(size_t)(int)v3 * 64 + lane]);
        float n0 = __int_as_float((int)(v0 >> 32));
        float n1 = __int_as_float((int)(v1 >> 32));
        float n2 = __int_as_float((int)(v2 >> 32));
        float n3 = __int_as_float((int)(v3 >> 32));
        ax = fmaf(r0.x, n0, ax); ay = fmaf(r0.y, n0, ay);
        ax = fmaf(r1.x, n1, ax); ay = fmaf(r1.y, n1, ay);
        ax = fmaf(r2.x, n2, ax); ay = fmaf(r2.y, n2, ay);
        ax = fmaf(r3.x, n3, ax); ay = fmaf(r3.y, n3, ay);
    }
    for (; j < end; j++) {
        long long v = __builtin_nontemporal_load(em + j);
        float2 r = __half22float2(hp[(size_t)(int)v * 64 + lane]);
        float nr = __int_as_float((int)(v >> 32));
        ax = fmaf(r.x, nr, ax); ay = fmaf(r.y, nr, ay);
    }
    float2 o;
    o.x = ax + bias[lane * 2];
    o.y = ay + bias[lane * 2 + 1];
    *(float2*)(B + (size_t)n * 128 + lane * 2) = o;
}

// ---- pool: batch sorted -> run-length, atomics only at transitions ------
__global__ __launch_bounds__(256) void pool_kernel(const float* __restrict__ B,
                                                   const int* __restrict__ batch,
                                                   float* pooled, float* cnt, int N) {
    int c = threadIdx.x & 127;
    int half = threadIdx.x >> 7;
    int n0 = blockIdx.x * 128;
    float acc = 0.f, cacc = 0.f;
    int curg = -1;
    for (int i = half; i < 128; i += 2) {
        int n = n0 + i;
        if (n >= N) break;
        int g = batch[n];
        float v = fmaxf(B[(size_t)n * 128 + c], 0.f);
        if (g != curg) {
            if (curg >= 0) {
                atomicAdd(&pooled[curg * 128 + c], acc);
                if (c == 0) atomicAdd(&cnt[curg], cacc);
            }
            curg = g; acc = 0.f; cacc = 0.f;
        }
        acc += v; cacc += 1.f;
    }
    if (curg >= 0) {
        atomicAdd(&pooled[curg * 128 + c], acc);
        if (c == 0) atomicAdd(&cnt[curg], cacc);
    }
}

// ---- head: one wave per graph ------------------------------------------
__global__ __launch_bounds__(64) void head_kernel(const float* __restrict__ pooled,
                                                  const float* __restrict__ cnt,
                                                  const float* __restrict__ Wfc1,
                                                  const float* __restrict__ bfc1,
                                                  const float* __restrict__ Wfc2,
                                                  const float* __restrict__ bfc2,
                                                  float* __restrict__ out) {
    __shared__ float mean[128];
    int g = blockIdx.x;
    int t = threadIdx.x;
    float inv = 1.0f / fmaxf(cnt[g], 1.0f);
    mean[t] = pooled[g * 128 + t] * inv;
    mean[t + 64] = pooled[g * 128 + t + 64] * inv;
    __syncthreads();
    float s = bfc1[t];
#pragma unroll 4
    for (int k = 0; k < 128; k++) s = fmaf(mean[k], Wfc1[k * 64 + t], s);
    float p = fmaxf(s, 0.f) * Wfc2[t];
#pragma unroll
    for (int o = 32; o > 0; o >>= 1) p += __shfl_down(p, o, 64);
    if (t == 0) out[g] = p + bfc2[0];
}

extern "C" void kernel_launch(void* const* d_in, const int* in_sizes, int n_in,
                              void* d_out, int out_size, void* d_ws, size_t ws_size,
                              hipStream_t stream) {
    const float* x    = (const float*)d_in[0];
    const int*   edge = (const int*)d_in[1];
    const int*   batch= (const int*)d_in[2];
    const float* W1   = (const float*)d_in[3];
    const float* b1   = (const float*)d_in[4];
    const float* W2   = (const float*)d_in[5];
    const float* b2   = (const float*)d_in[6];
    const float* Wfc1 = (const float*)d_in[7];
    const float* bfc1 = (const float*)d_in[8];
    const float* Wfc2 = (const float*)d_in[9];
    const float* bfc2 = (const float*)d_in[10];
    float* out = (float*)d_out;

    int N = in_sizes[0] / 128;
    int E = in_sizes[1] / 2;
    const int* src = edge;
    const int* dst = edge + E;

    char* ws = (char*)d_ws;
    size_t off = 0;
    auto alloc = [&](size_t bytes) { void* p = ws + off; off += (bytes + 255) & ~(size_t)255; return p; };
    __half* Ah    = (__half*)alloc((size_t)N * 128 * sizeof(__half));   // gather operand
    float* B      = (float*)alloc((size_t)N * 128 * sizeof(float));     // gather out
    float* dinv   = (float*)alloc((size_t)N * sizeof(float));
    int*   count  = (int*)alloc((size_t)N * sizeof(int));
    int*   tmp    = (int*)alloc((size_t)N * sizeof(int));
    int*   rowptr = (int*)alloc((size_t)(N + 1) * sizeof(int));
    int*   cursor = (int*)alloc((size_t)N * sizeof(int));
    int2*  em     = (int2*)alloc((size_t)E * sizeof(int2));
    int*   bsum   = (int*)alloc(256 * sizeof(int));
    int*   boff   = (int*)alloc(256 * sizeof(int));
    float* pooled = (float*)alloc(64 * 128 * sizeof(float));
    float* cnt    = (float*)alloc(64 * sizeof(float));
    unsigned short* W1h = (unsigned short*)alloc(16384 * sizeof(short));
    unsigned short* W1l = (unsigned short*)alloc(16384 * sizeof(short));
    unsigned short* W2h = (unsigned short*)alloc(16384 * sizeof(short));
    unsigned short* W2l = (unsigned short*)alloc(16384 * sizeof(short));

    int nb = (N + 255) / 256;

    (void)hipMemsetAsync(count, 0, (size_t)N * sizeof(int), stream);

    // CSR build + weight prep (pooled/cnt zeroed in scan2_wconv blk 0)
    hist_kernel<<<(E + 255) / 256, 256, 0, stream>>>(dst, count, E);
    scan1_kernel<<<nb, 256, 0, stream>>>(count, tmp, bsum, N);
    scan2_wconv<<<129, 256, 0, stream>>>(bsum, boff, nb, pooled, cnt,
                                         W1, W2, W1h, W1l, W2h, W2l);
    finalize_kernel<<<(N + 256) / 256, 256, 0, stream>>>(count, tmp, boff, rowptr, cursor, dinv, N);
    reorder_kernel<<<(E + 255) / 256, 256, 0, stream>>>(src, dst, dinv, cursor, em, E);

    int gblocks = (N + 63) / 64;
    int ablocks = (N + 3) / 4;

    // Layer 1
    gemm_mfma<false><<<gblocks, 256, 0, stream>>>(x, W1h, W1l, Ah, N);
    gather_half<<<ablocks, 256, 0, stream>>>(Ah, dinv, b1, rowptr, (const long long*)em, B, N);

    // Layer 2 (relu fused into GEMM staging)
    gemm_mfma<true><<<gblocks, 256, 0, stream>>>(B, W2h, W2l, Ah, N);
    gather_half<<<ablocks, 256, 0, stream>>>(Ah, dinv, b2, rowptr, (const long long*)em, B, N);

    // Pool (relu fused) + head
    pool_kernel<<<(N + 127) / 128, 256, 0, stream>>>(B, batch, pooled, cnt, N);
    head_kernel<<<64, 64, 0, stream>>>(pooled, cnt, Wfc1, bfc1, Wfc2, bfc2, out);
}

// Round 13
// 278.495 us; speedup vs baseline: 1.1012x; 1.0463x over previous
//
#include <hip/hip_runtime.h>
#include <hip/hip_fp16.h>

// ---------------------------------------------------------------------------
// GCN pipeline. Round 13 = exact round-9 revert (validated best, 279.6 µs).
//  - GEMM: LDS-staged bf16x3 MFMA, frag-ordered W, fp16 output via LDS repack
//  - gather: wave/node, half2 row reads (256B/txn), 8x unroll, fp32 accum
//    (plain cached em loads — nt variant regressed, r12)
//  - pool: run-length (atomics only at graph transitions)
// ---------------------------------------------------------------------------

typedef short bf16x8 __attribute__((ext_vector_type(8)));
typedef float f32x4  __attribute__((ext_vector_type(4)));

__device__ inline unsigned short f2bf_rne(float f) {
    unsigned u = __float_as_uint(f);
    unsigned r = (u + 0x7fffu + ((u >> 16) & 1u)) >> 16;
    return (unsigned short)r;
}
__device__ inline float bf2f(unsigned short h) {
    return __uint_as_float(((unsigned)h) << 16);
}

__global__ void hist_kernel(const int* __restrict__ dst, int* __restrict__ count, int E) {
    int e = blockIdx.x * blockDim.x + threadIdx.x;
    if (e < E) atomicAdd(&count[dst[e]], 1);
}

__global__ __launch_bounds__(256) void scan1_kernel(const int* __restrict__ count,
                                                    int* __restrict__ tmp,
                                                    int* __restrict__ bsum, int N) {
    __shared__ int s[256];
    int tid = threadIdx.x;
    int i = blockIdx.x * 256 + tid;
    int v = (i < N) ? count[i] : 0;
    s[tid] = v;
    __syncthreads();
#pragma unroll
    for (int off = 1; off < 256; off <<= 1) {
        int t = (tid >= off) ? s[tid - off] : 0;
        __syncthreads();
        s[tid] += t;
        __syncthreads();
    }
    if (i < N) tmp[i] = s[tid];
    if (tid == 255) bsum[blockIdx.x] = s[255];
}

// block 0: exclusive scan of block sums + zero pooled/cnt.
// blocks 1..128: weight split/transpose into MFMA fragment order.
// frag addr = ((ct*4+ks)*64 + (q*16+nn))*8 + j ; n=ct*16+nn, k=ks*32+q*8+j
__global__ __launch_bounds__(256) void scan2_wconv(const int* __restrict__ bsum,
                                                   int* __restrict__ boff, int nb,
                                                   float* __restrict__ pooled,
                                                   float* __restrict__ cnt,
                                                   const float* __restrict__ W1,
                                                   const float* __restrict__ W2,
                                                   unsigned short* __restrict__ W1h,
                                                   unsigned short* __restrict__ W1l,
                                                   unsigned short* __restrict__ W2h,
                                                   unsigned short* __restrict__ W2l) {
    int tid = threadIdx.x;
    if (blockIdx.x == 0) {
        __shared__ int s[256];
        int v = (tid < nb) ? bsum[tid] : 0;
        s[tid] = v;
        __syncthreads();
#pragma unroll
        for (int off = 1; off < 256; off <<= 1) {
            int t = (tid >= off) ? s[tid - off] : 0;
            __syncthreads();
            s[tid] += t;
            __syncthreads();
        }
        if (tid < nb) boff[tid] = s[tid] - v;   // exclusive
        for (int i = tid; i < 64 * 128; i += 256) pooled[i] = 0.f;
        if (tid < 64) cnt[tid] = 0.f;
        return;
    }
    int i = (blockIdx.x - 1) * 256 + tid;       // 0..32767
    const float* W = (i < 16384) ? W1 : W2;
    unsigned short* Wh = (i < 16384) ? W1h : W2h;
    unsigned short* Wl = (i < 16384) ? W1l : W2l;
    int ii = i & 16383;
    int k = ii >> 7, n = ii & 127;
    float v = W[ii];
    unsigned short h = f2bf_rne(v);
    float lo = v - bf2f(h);
    int ct = n >> 4, nn = n & 15, ks = k >> 5, q = (k >> 3) & 3, j = k & 7;
    int oidx = (((ct * 4 + ks) * 64) + (q * 16 + nn)) * 8 + j;
    Wh[oidx] = h;
    Wl[oidx] = f2bf_rne(lo);
}

// rowptr (exclusive), cursor copy, dinv
__global__ void finalize_kernel(const int* __restrict__ count, const int* __restrict__ tmp,
                                const int* __restrict__ boff, int* __restrict__ rowptr,
                                int* __restrict__ cursor, float* __restrict__ dinv, int N) {
    int i = blockIdx.x * blockDim.x + threadIdx.x;
    if (i > N) return;
    int ex = (i == 0) ? 0 : tmp[i - 1] + boff[(i - 1) >> 8];
    rowptr[i] = ex;
    if (i < N) {
        cursor[i] = ex;
        dinv[i] = 1.0f / sqrtf((float)count[i] + 1.0f);
    }
}

__global__ void reorder_kernel(const int* __restrict__ src, const int* __restrict__ dst,
                               const float* __restrict__ dinv,
                               int* __restrict__ cursor, int2* __restrict__ em, int E) {
    int e = blockIdx.x * blockDim.x + threadIdx.x;
    if (e < E) {
        int s = src[e], d = dst[e];
        int pos = atomicAdd(&cursor[d], 1);
        float norm = dinv[s] * dinv[d];
        em[pos] = make_int2(s, __float_as_int(norm));
    }
}

// ---- GEMM: OUT_fp16[M,128] = act(X_f32) @ W via bf16x3 MFMA -------------
template <bool RELU_IN>
__global__ __launch_bounds__(256) void gemm_mfma(const float* __restrict__ X,
                                                 const unsigned short* __restrict__ Wfh,
                                                 const unsigned short* __restrict__ Wfl,
                                                 __half* __restrict__ OUT, int M) {
    __shared__ unsigned short Xh[64][136];
    __shared__ unsigned short Xl[64][136];
    int tid = threadIdx.x;
    int w = tid >> 6, l = tid & 63;
    int m0 = blockIdx.x * 64;

#pragma unroll
    for (int it = 0; it < 8; it++) {
        int i = tid + it * 256;
        int row = i >> 5, c4 = i & 31;
        int grow = m0 + row;
        float4 v = make_float4(0.f, 0.f, 0.f, 0.f);
        if (grow < M) v = *(const float4*)(X + (size_t)grow * 128 + c4 * 4);
        if (RELU_IN) {
            v.x = fmaxf(v.x, 0.f); v.y = fmaxf(v.y, 0.f);
            v.z = fmaxf(v.z, 0.f); v.w = fmaxf(v.w, 0.f);
        }
        float a[4] = {v.x, v.y, v.z, v.w};
        ushort4 hi, lo;
        unsigned short* hp = (unsigned short*)&hi;
        unsigned short* lp = (unsigned short*)&lo;
#pragma unroll
        for (int e = 0; e < 4; e++) {
            unsigned short h = f2bf_rne(a[e]);
            hp[e] = h;
            lp[e] = f2bf_rne(a[e] - bf2f(h));
        }
        *(ushort4*)&Xh[row][c4 * 4] = hi;
        *(ushort4*)&Xl[row][c4 * 4] = lo;
    }
    __syncthreads();

    int q = l >> 4, nn = l & 15;
    f32x4 acc[8];
#pragma unroll
    for (int ct = 0; ct < 8; ct++) acc[ct] = (f32x4){0.f, 0.f, 0.f, 0.f};

#pragma unroll
    for (int ks = 0; ks < 4; ks++) {
        bf16x8 ahi = *(const bf16x8*)&Xh[w * 16 + nn][ks * 32 + q * 8];
        bf16x8 alo = *(const bf16x8*)&Xl[w * 16 + nn][ks * 32 + q * 8];
#pragma unroll
        for (int ct = 0; ct < 8; ct++) {
            size_t fo = ((size_t)(ct * 4 + ks) * 64 + l) * 8;
            bf16x8 bhi = *(const bf16x8*)(Wfh + fo);
            bf16x8 blo = *(const bf16x8*)(Wfl + fo);
            acc[ct] = __builtin_amdgcn_mfma_f32_16x16x32_bf16(ahi, bhi, acc[ct], 0, 0, 0);
            acc[ct] = __builtin_amdgcn_mfma_f32_16x16x32_bf16(alo, bhi, acc[ct], 0, 0, 0);
            acc[ct] = __builtin_amdgcn_mfma_f32_16x16x32_bf16(ahi, blo, acc[ct], 0, 0, 0);
        }
    }
    __syncthreads();   // done with Xh — reuse as fp16 epilogue buffer

#pragma unroll
    for (int r = 0; r < 4; r++) {
        int lrow = w * 16 + q * 4 + r;
#pragma unroll
        for (int ct = 0; ct < 8; ct++) {
            __half hv = __float2half(acc[ct][r]);
            Xh[lrow][ct * 16 + nn] = __half_as_ushort(hv);
        }
    }
    __syncthreads();
#pragma unroll
    for (int t = 0; t < 4; t++) {
        int c = tid + t * 256;
        int row = c >> 4, seg = c & 15;
        int grow = m0 + row;
        if (grow < M) {
            uint4 v = *(uint4*)&Xh[row][seg * 8];
            *(uint4*)((unsigned short*)OUT + (size_t)grow * 128 + seg * 8) = v;
        }
    }
}

// ---- gather: wave/node, fp16 operand, fp32 accum/out, 8x unroll ---------
__global__ __launch_bounds__(256) void gather_half(const __half* __restrict__ h,
                                                   const float* __restrict__ dinv,
                                                   const float* __restrict__ bias,
                                                   const int* __restrict__ rowptr,
                                                   const long long* __restrict__ em,
                                                   float* __restrict__ B, int N) {
    int n = blockIdx.x * 4 + (threadIdx.x >> 6);
    int lane = threadIdx.x & 63;
    if (n >= N) return;
    int beg = rowptr[n], end = rowptr[n + 1];
    float din = dinv[n];
    const __half2* hp = (const __half2*)h;        // [N*64]
    float2 hv = __half22float2(hp[(size_t)n * 64 + lane]);
    float sw = din * din;
    float ax = hv.x * sw, ay = hv.y * sw;
    int j = beg;
    for (; j + 8 <= end; j += 8) {
        long long v0 = em[j],     v1 = em[j + 1], v2 = em[j + 2], v3 = em[j + 3];
        long long v4 = em[j + 4], v5 = em[j + 5], v6 = em[j + 6], v7 = em[j + 7];
        float2 r0 = __half22float2(hp[(size_t)(int)v0 * 64 + lane]);
        float2 r1 = __half22float2(hp[(size_t)(int)v1 * 64 + lane]);
        float2 r2 = __half22float2(hp[(size_t)(int)v2 * 64 + lane]);
        float2 r3 = __half22float2(hp[(size_t)(int)v3 * 64 + lane]);
        float2 r4 = __half22float2(hp[(size_t)(int)v4 * 64 + lane]);
        float2 r5 = __half22float2(hp[(size_t)(int)v5 * 64 + lane]);
        float2 r6 = __half22float2(hp[(size_t)(int)v6 * 64 + lane]);
        float2 r7 = __half22float2(hp[(size_t)(int)v7 * 64 + lane]);
        float n0 = __int_as_float((int)(v0 >> 32));
        float n1 = __int_as_float((int)(v1 >> 32));
        float n2 = __int_as_float((int)(v2 >> 32));
        float n3 = __int_as_float((int)(v3 >> 32));
        float n4 = __int_as_float((int)(v4 >> 32));
        float n5 = __int_as_float((int)(v5 >> 32));
        float n6 = __int_as_float((int)(v6 >> 32));
        float n7 = __int_as_float((int)(v7 >> 32));
        ax = fmaf(r0.x, n0, ax); ay = fmaf(r0.y, n0, ay);
        ax = fmaf(r1.x, n1, ax); ay = fmaf(r1.y, n1, ay);
        ax = fmaf(r2.x, n2, ax); ay = fmaf(r2.y, n2, ay);
        ax = fmaf(r3.x, n3, ax); ay = fmaf(r3.y, n3, ay);
        ax = fmaf(r4.x, n4, ax); ay = fmaf(r4.y, n4, ay);
        ax = fmaf(r5.x, n5, ax); ay = fmaf(r5.y, n5, ay);
        ax = fmaf(r6.x, n6, ax); ay = fmaf(r6.y, n6, ay);
        ax = fmaf(r7.x, n7, ax); ay = fmaf(r7.y, n7, ay);
    }
    for (; j + 4 <= end; j += 4) {
        long long v0 = em[j], v1 = em[j + 1], v2 = em[j + 2], v3 = em[j + 3];
        float2 r0 = __half22float2(hp[(size_t)(int)v0 * 64 + lane]);
        float2 r1 = __half22float2(hp[(size_t)(int)v1 * 64 + lane]);
        float2 r2 = __half22float2(hp[(size_t)(int)v2 * 64 + lane]);
        float2 r3 = __half22float2(hp[(size_t)(int)v3 * 64 + lane]);
        float n0 = __int_as_float((int)(v0 >> 32));
        float n1 = __int_as_float((int)(v1 >> 32));
        float n2 = __int_as_float((int)(v2 >> 32));
        float n3 = __int_as_float((int)(v3 >> 32));
        ax = fmaf(r0.x, n0, ax); ay = fmaf(r0.y, n0, ay);
        ax = fmaf(r1.x, n1, ax); ay = fmaf(r1.y, n1, ay);
        ax = fmaf(r2.x, n2, ax); ay = fmaf(r2.y, n2, ay);
        ax = fmaf(r3.x, n3, ax); ay = fmaf(r3.y, n3, ay);
    }
    for (; j < end; j++) {
        long long v = em[j];
        float2 r = __half22float2(hp[(size_t)(int)v * 64 + lane]);
        float nr = __int_as_float((int)(v >> 32));
        ax = fmaf(r.x, nr, ax); ay = fmaf(r.y, nr, ay);
    }
    float2 o;
    o.x = ax + bias[lane * 2];
    o.y = ay + bias[lane * 2 + 1];
    *(float2*)(B + (size_t)n * 128 + lane * 2) = o;
}

// ---- pool: batch sorted -> run-length, atomics only at transitions ------
__global__ __launch_bounds__(256) void pool_kernel(const float* __restrict__ B,
                                                   const int* __restrict__ batch,
                                                   float* pooled, float* cnt, int N) {
    int c = threadIdx.x & 127;
    int half = threadIdx.x >> 7;
    int n0 = blockIdx.x * 128;
    float acc = 0.f, cacc = 0.f;
    int curg = -1;
    for (int i = half; i < 128; i += 2) {
        int n = n0 + i;
        if (n >= N) break;
        int g = batch[n];
        float v = fmaxf(B[(size_t)n * 128 + c], 0.f);
        if (g != curg) {
            if (curg >= 0) {
                atomicAdd(&pooled[curg * 128 + c], acc);
                if (c == 0) atomicAdd(&cnt[curg], cacc);
            }
            curg = g; acc = 0.f; cacc = 0.f;
        }
        acc += v; cacc += 1.f;
    }
    if (curg >= 0) {
        atomicAdd(&pooled[curg * 128 + c], acc);
        if (c == 0) atomicAdd(&cnt[curg], cacc);
    }
}

// ---- head: one wave per graph ------------------------------------------
__global__ __launch_bounds__(64) void head_kernel(const float* __restrict__ pooled,
                                                  const float* __restrict__ cnt,
                                                  const float* __restrict__ Wfc1,
                                                  const float* __restrict__ bfc1,
                                                  const float* __restrict__ Wfc2,
                                                  const float* __restrict__ bfc2,
                                                  float* __restrict__ out) {
    __shared__ float mean[128];
    int g = blockIdx.x;
    int t = threadIdx.x;
    float inv = 1.0f / fmaxf(cnt[g], 1.0f);
    mean[t] = pooled[g * 128 + t] * inv;
    mean[t + 64] = pooled[g * 128 + t + 64] * inv;
    __syncthreads();
    float s = bfc1[t];
#pragma unroll 4
    for (int k = 0; k < 128; k++) s = fmaf(mean[k], Wfc1[k * 64 + t], s);
    float p = fmaxf(s, 0.f) * Wfc2[t];
#pragma unroll
    for (int o = 32; o > 0; o >>= 1) p += __shfl_down(p, o, 64);
    if (t == 0) out[g] = p + bfc2[0];
}

extern "C" void kernel_launch(void* const* d_in, const int* in_sizes, int n_in,
                              void* d_out, int out_size, void* d_ws, size_t ws_size,
                              hipStream_t stream) {
    const float* x    = (const float*)d_in[0];
    const int*   edge = (const int*)d_in[1];
    const int*   batch= (const int*)d_in[2];
    const float* W1   = (const float*)d_in[3];
    const float* b1   = (const float*)d_in[4];
    const float* W2   = (const float*)d_in[5];
    const float* b2   = (const float*)d_in[6];
    const float* Wfc1 = (const float*)d_in[7];
    const float* bfc1 = (const float*)d_in[8];
    const float* Wfc2 = (const float*)d_in[9];
    const float* bfc2 = (const float*)d_in[10];
    float* out = (float*)d_out;

    int N = in_sizes[0] / 128;
    int E = in_sizes[1] / 2;
    const int* src = edge;
    const int* dst = edge + E;

    char* ws = (char*)d_ws;
    size_t off = 0;
    auto alloc = [&](size_t bytes) { void* p = ws + off; off += (bytes + 255) & ~(size_t)255; return p; };
    __half* Ah    = (__half*)alloc((size_t)N * 128 * sizeof(__half));   // gather operand
    float* B      = (float*)alloc((size_t)N * 128 * sizeof(float));     // gather out
    float* dinv   = (float*)alloc((size_t)N * sizeof(float));
    int*   count  = (int*)alloc((size_t)N * sizeof(int));
    int*   tmp    = (int*)alloc((size_t)N * sizeof(int));
    int*   rowptr = (int*)alloc((size_t)(N + 1) * sizeof(int));
    int*   cursor = (int*)alloc((size_t)N * sizeof(int));
    int2*  em     = (int2*)alloc((size_t)E * sizeof(int2));
    int*   bsum   = (int*)alloc(256 * sizeof(int));
    int*   boff   = (int*)alloc(256 * sizeof(int));
    float* pooled = (float*)alloc(64 * 128 * sizeof(float));
    float* cnt    = (float*)alloc(64 * sizeof(float));
    unsigned short* W1h = (unsigned short*)alloc(16384 * sizeof(short));
    unsigned short* W1l = (unsigned short*)alloc(16384 * sizeof(short));
    unsigned short* W2h = (unsigned short*)alloc(16384 * sizeof(short));
    unsigned short* W2l = (unsigned short*)alloc(16384 * sizeof(short));

    int nb = (N + 255) / 256;

    (void)hipMemsetAsync(count, 0, (size_t)N * sizeof(int), stream);

    // CSR build + weight prep (pooled/cnt zeroed in scan2_wconv blk 0)
    hist_kernel<<<(E + 255) / 256, 256, 0, stream>>>(dst, count, E);
    scan1_kernel<<<nb, 256, 0, stream>>>(count, tmp, bsum, N);
    scan2_wconv<<<129, 256, 0, stream>>>(bsum, boff, nb, pooled, cnt,
                                         W1, W2, W1h, W1l, W2h, W2l);
    finalize_kernel<<<(N + 256) / 256, 256, 0, stream>>>(count, tmp, boff, rowptr, cursor, dinv, N);
    reorder_kernel<<<(E + 255) / 256, 256, 0, stream>>>(src, dst, dinv, cursor, em, E);

    int gblocks = (N + 63) / 64;
    int ablocks = (N + 3) / 4;

    // Layer 1
    gemm_mfma<false><<<gblocks, 256, 0, stream>>>(x, W1h, W1l, Ah, N);
    gather_half<<<ablocks, 256, 0, stream>>>(Ah, dinv, b1, rowptr, (const long long*)em, B, N);

    // Layer 2 (relu fused into GEMM staging)
    gemm_mfma<true><<<gblocks, 256, 0, stream>>>(B, W2h, W2l, Ah, N);
    gather_half<<<ablocks, 256, 0, stream>>>(Ah, dinv, b2, rowptr, (const long long*)em, B, N);

    // Pool (relu fused) + head
    pool_kernel<<<(N + 127) / 128, 256, 0, stream>>>(B, batch, pooled, cnt, N);
    head_kernel<<<64, 64, 0, stream>>>(pooled, cnt, Wfc1, bfc1, Wfc2, bfc2, out);
}